// Round 1
// baseline (6628.580 us; speedup 1.0000x reference)
//
#include <hip/hip_runtime.h>
#include <math.h>

// ---------------- constants ----------------
#define N_SRC 1024
#define HIDC 256
#define VHW 1024
#define FHW 256

__device__ __forceinline__ float gelu_f(float x){
  return 0.5f * x * (1.0f + erff(x * 0.70710678118654752440f));
}

__device__ __forceinline__ void fma4(float& a, const float4 x, const float4 w){
  a = fmaf(x.x, w.x, a); a = fmaf(x.y, w.y, a); a = fmaf(x.z, w.z, a); a = fmaf(x.w, w.w, a);
}
__device__ __forceinline__ void fma4s(float4& a, float s, const float4 w){
  a.x = fmaf(s, w.x, a.x); a.y = fmaf(s, w.y, a.y); a.z = fmaf(s, w.z, a.z); a.w = fmaf(s, w.w, a.w);
}

// ---------------- gaussian tables (match numpy f64 then cast) ----------------
__global__ void k_gauss(float* __restrict__ gbn, float* __restrict__ gst){
  __shared__ double red[256];
  int t = threadIdx.x;
  {
    double v = 0.0;
    if (t < 121){
      int r = t / 11, c = t % 11;
      double y = -1.0 + 2.0 * (double)r / 10.0;
      double x = -1.0 + 2.0 * (double)c / 10.0;
      v = exp(-(x*x + y*y) / (2.0 * 0.4 * 0.4));
    }
    red[t] = v; __syncthreads();
    for (int s = 128; s > 0; s >>= 1){ if (t < s) red[t] += red[t+s]; __syncthreads(); }
    double sum = red[0];
    __syncthreads();
    if (t < 121) gbn[t] = (float)(v / sum);
    __syncthreads();
  }
  {
    double vals[4]; double loc = 0.0;
    #pragma unroll
    for (int i = 0; i < 4; ++i){
      int j = t + 256*i;
      double v = 0.0;
      if (j < 961){
        int r = j / 31, c = j % 31;
        double y = -1.0 + 2.0 * (double)r / 30.0;
        double x = -1.0 + 2.0 * (double)c / 30.0;
        v = exp(-(x*x + y*y) / (2.0 * 0.4 * 0.4));
      }
      vals[i] = v; loc += v;
    }
    red[t] = loc; __syncthreads();
    for (int s = 128; s > 0; s >>= 1){ if (t < s) red[t] += red[t+s]; __syncthreads(); }
    double sum = red[0];
    __syncthreads();
    #pragma unroll
    for (int i = 0; i < 4; ++i){
      int j = t + 256*i;
      if (j < 961) gst[j] = (float)(vals[i] / sum);
    }
  }
}

// ---------------- weight transposes ----------------
__global__ void k_trans(const float* __restrict__ pw1_w, const float* __restrict__ pw2_w,
                        const float* __restrict__ bn_w,
                        const float* __restrict__ st1_w, const float* __restrict__ st2_w,
                        float* __restrict__ W1T, float* __restrict__ W2T, float* __restrict__ bnWT,
                        float* __restrict__ Wt1, float* __restrict__ Wt2){
  int stride = gridDim.x * blockDim.x;
  int i0 = blockIdx.x * blockDim.x + threadIdx.x;
  for (int e = i0; e < 256*1024; e += stride){ int k = e >> 10, c = e & 1023; W1T[e] = pw1_w[c*256 + k]; }
  for (int e = i0; e < 1024*256; e += stride){ int hk = e >> 8, o = e & 255; W2T[e] = pw2_w[o*1024 + hk]; }
  for (int e = i0; e < 256*128; e += stride){ int c = e >> 7, o = e & 127; bnWT[e] = bn_w[o*256 + c]; }
  for (int e = i0; e < 64*9*64; e += stride){
    int co = e / 576, r = e % 576, d = r >> 6, ci = r & 63;
    Wt1[e] = st1_w[(co*64 + ci)*9 + d];
    Wt2[e] = st2_w[(co*64 + ci)*9 + d];
  }
}

// ---------------- shared 3x3 conv body (x-quad register tiling) ----------------
// in_t layout: [(gr*33+gc)*68 + ci], all-lane-broadcast reads.
__device__ __forceinline__ void conv_body(const float* __restrict__ in_t,
                                          const float* __restrict__ Wt,
                                          int co, int sg, int nq, float acc[8][4]){
  for (int ciq = 0; ciq < 16; ++ciq){
    float4 w[9];
    #pragma unroll
    for (int d = 0; d < 9; ++d)
      w[d] = *reinterpret_cast<const float4*>(&Wt[((co*9 + d) << 6) + (ciq << 2)]);
    #pragma unroll
    for (int j = 0; j < 8; ++j){
      int q = sg + 4*j;
      if (q < nq){
        int ly = q >> 3, xq = (q & 7) << 2;
        #pragma unroll
        for (int dy = 0; dy < 3; ++dy){
          const float* rp = &in_t[((ly + dy)*33 + xq)*68 + (ciq << 2)];
          float4 A0 = *(const float4*)(rp);
          float4 A1 = *(const float4*)(rp + 68);
          float4 A2 = *(const float4*)(rp + 136);
          float4 A3 = *(const float4*)(rp + 204);
          float4 A4 = *(const float4*)(rp + 272);
          float4 A5 = *(const float4*)(rp + 340);
          fma4(acc[j][0], A0, w[dy*3+0]); fma4(acc[j][0], A1, w[dy*3+1]); fma4(acc[j][0], A2, w[dy*3+2]);
          fma4(acc[j][1], A1, w[dy*3+0]); fma4(acc[j][1], A2, w[dy*3+1]); fma4(acc[j][1], A3, w[dy*3+2]);
          fma4(acc[j][2], A2, w[dy*3+0]); fma4(acc[j][2], A3, w[dy*3+1]); fma4(acc[j][2], A4, w[dy*3+2]);
          fma4(acc[j][3], A3, w[dy*3+0]); fma4(acc[j][3], A4, w[dy*3+1]); fma4(acc[j][3], A5, w[dy*3+2]);
        }
      }
    }
  }
}

// ---------------- st path: fused gather + conv1 + gelu ----------------
__global__ __launch_bounds__(256) void k_st_conv1(
    const float* __restrict__ vis, const float* __restrict__ pos,
    const float* __restrict__ Wt1, const float* __restrict__ st1_b,
    float* __restrict__ g1)
{
  __shared__ float in_t[(6*33 + 8) * 68];
  int n = blockIdx.x, band = blockIdx.y;
  int y0 = band * 4;
  int R = min(4, 31 - y0);
  int t = threadIdx.x;
  float px = pos[2*n], py = pos[2*n + 1];

  int npts = (R + 2) * 33 * 64;
  for (int gidx = t; gidx < npts; gidx += 256){
    int gc = gidx % 33;
    int tmp = gidx / 33;
    int ch = tmp & 63;
    int gr = tmp >> 6;
    int r = y0 - 1 + gr;
    int c = gc - 1;
    float val = 0.0f;
    if (r >= 0 && r < 31 && c >= 0 && c < 31){
      float xsf = fminf(fmaxf(px + (float)(c - 15), 0.0f), 1023.0f);
      float ysf = fminf(fmaxf(py + (float)(r - 15), 0.0f), 1023.0f);
      int x0 = min(max((int)floorf(xsf), 0), 1022);
      int y0i = min(max((int)floorf(ysf), 0), 1022);
      float wx = xsf - (float)x0, wy = ysf - (float)y0i;
      const float* b = vis + (size_t)ch * (VHW*VHW) + (size_t)y0i * VHW + x0;
      float v00 = b[0], v01 = b[1], v10 = b[VHW], v11 = b[VHW+1];
      val = v00*(1.f-wy)*(1.f-wx) + v01*(1.f-wy)*wx + v10*wy*(1.f-wx) + v11*wy*wx;
    }
    in_t[(gr*33 + gc)*68 + ch] = val;
  }
  __syncthreads();

  int co = t & 63, sg = t >> 6;
  int nq = R * 8;
  float acc[8][4];
  #pragma unroll
  for (int j = 0; j < 8; ++j){ acc[j][0]=0.f; acc[j][1]=0.f; acc[j][2]=0.f; acc[j][3]=0.f; }

  conv_body(in_t, Wt1, co, sg, nq, acc);

  float bco = st1_b[co];
  #pragma unroll
  for (int j = 0; j < 8; ++j){
    int q = sg + 4*j;
    if (q < nq){
      int ly = q >> 3, xq = (q & 7) << 2;
      int y = y0 + ly;
      #pragma unroll
      for (int p = 0; p < 4; ++p){
        int x = xq + p;
        if (x < 31)
          g1[(((size_t)n*31 + y)*31 + x)*64 + co] = gelu_f(acc[j][p] + bco);
      }
    }
  }
}

// ---------------- st path: conv2 + gelu + gaussian reduce ----------------
__global__ __launch_bounds__(256) void k_st_conv2(
    const float* __restrict__ g1, const float* __restrict__ gst,
    const float* __restrict__ Wt2, const float* __restrict__ st2_b,
    float* __restrict__ st_vec)
{
  __shared__ float in_t[(6*33 + 8) * 68];
  __shared__ float red[256];
  int n = blockIdx.x, band = blockIdx.y;
  int y0 = band * 4;
  int R = min(4, 31 - y0);
  int t = threadIdx.x;

  int npts = (R + 2) * 33;
  for (int task = t; task < npts*16; task += 256){
    int pt = task >> 4, l16 = task & 15;
    int gr = pt / 33, gc = pt % 33;
    int r = y0 - 1 + gr, c = gc - 1;
    float4 v = {0.f,0.f,0.f,0.f};
    if (r >= 0 && r < 31 && c >= 0 && c < 31)
      v = *(const float4*)&g1[(((size_t)n*31 + r)*31 + c)*64 + l16*4];
    *(float4*)&in_t[(gr*33 + gc)*68 + l16*4] = v;
  }
  __syncthreads();

  int co = t & 63, sg = t >> 6;
  int nq = R * 8;
  float acc[8][4];
  #pragma unroll
  for (int j = 0; j < 8; ++j){ acc[j][0]=0.f; acc[j][1]=0.f; acc[j][2]=0.f; acc[j][3]=0.f; }

  conv_body(in_t, Wt2, co, sg, nq, acc);

  float bco = st2_b[co];
  float vacc = 0.f;
  #pragma unroll
  for (int j = 0; j < 8; ++j){
    int q = sg + 4*j;
    if (q < nq){
      int ly = q >> 3, xq = (q & 7) << 2;
      int y = y0 + ly;
      #pragma unroll
      for (int p = 0; p < 4; ++p){
        int x = xq + p;
        if (x < 31) vacc += gst[y*31 + x] * gelu_f(acc[j][p] + bco);
      }
    }
  }
  red[t] = vacc; __syncthreads();
  if (t < 64)
    atomicAdd(&st_vec[n*64 + t], red[t] + red[t+64] + red[t+128] + red[t+192]);
}

// ---------------- bn path: gather windows -> [n][121][256] ----------------
__global__ __launch_bounds__(256) void k_bn_gather(
  const float* __restrict__ bott, const float* __restrict__ pos, float* __restrict__ bn_win)
{
  __shared__ float tile[121*65];
  int n = blockIdx.x, t = threadIdx.x;
  float pbx = (pos[2*n]   + 0.5f)*0.25f - 0.5f;
  float pby = (pos[2*n+1] + 0.5f)*0.25f - 0.5f;
  for (int c4 = 0; c4 < 4; ++c4){
    int ch0 = c4 * 64;
    for (int idx = t; idx < 121*64; idx += 256){
      int chl = idx / 121, p = idx % 121;
      int r = p / 11, c = p % 11;
      float xsf = fminf(fmaxf(pbx + (float)(c-5), 0.f), 255.f);
      float ysf = fminf(fmaxf(pby + (float)(r-5), 0.f), 255.f);
      int x0 = min(max((int)floorf(xsf),0), 254);
      int y0i = min(max((int)floorf(ysf),0), 254);
      float wx = xsf - (float)x0, wy = ysf - (float)y0i;
      const float* b = bott + (size_t)(ch0+chl)*(FHW*FHW) + y0i*FHW + x0;
      float val = b[0]*(1.f-wy)*(1.f-wx) + b[1]*(1.f-wy)*wx + b[FHW]*wy*(1.f-wx) + b[FHW+1]*wy*wx;
      tile[p*65 + chl] = val;
    }
    __syncthreads();
    for (int idx = t; idx < 121*64; idx += 256){
      int p = idx >> 6, j = idx & 63;
      bn_win[((size_t)n*121 + p)*256 + ch0 + j] = tile[p*65 + j];
    }
    __syncthreads();
  }
}

// ---------------- bn path: depthwise 7x7 + bias ----------------
__global__ __launch_bounds__(256) void k_dwconv(
  const float* __restrict__ bn_win, const float* __restrict__ dw_w, const float* __restrict__ dw_b,
  float* __restrict__ dco)
{
  __shared__ float in_t[121*65];
  int n = blockIdx.x, c4 = blockIdx.y, t = threadIdx.x;
  int ch0 = c4*64;
  for (int idx = t; idx < 121*64; idx += 256){
    int p = idx >> 6, j = idx & 63;
    in_t[p*65 + j] = bn_win[((size_t)n*121 + p)*256 + ch0 + j];
  }
  int chl = t & 63;
  float w[49];
  #pragma unroll
  for (int k = 0; k < 49; ++k) w[k] = dw_w[(ch0 + chl)*49 + k];
  float bias = dw_b[ch0 + chl];
  __syncthreads();
  for (int sp = (t >> 6); sp < 121; sp += 4){
    int r = sp / 11, c = sp % 11;
    float a = bias;
    #pragma unroll
    for (int dy = 0; dy < 7; ++dy){
      int ry = r + dy - 3;
      if (ry < 0 || ry > 10) continue;
      #pragma unroll
      for (int dx = 0; dx < 7; ++dx){
        int cx = c + dx - 3;
        if (cx < 0 || cx > 10) continue;
        a = fmaf(in_t[(ry*11 + cx)*65 + chl], w[dy*7 + dx], a);
      }
    }
    dco[((size_t)n*121 + sp)*256 + ch0 + chl] = a;
  }
}

// ---------------- bn path: layernorm (in place), one wave per row ----------------
__global__ __launch_bounds__(256) void k_ln(
  float* __restrict__ dco, const float* __restrict__ ln_g, const float* __restrict__ ln_b)
{
  int m = blockIdx.x*4 + (threadIdx.x >> 6);
  int lane = threadIdx.x & 63;
  float4 v = *(float4*)&dco[(size_t)m*256 + lane*4];
  float s  = v.x+v.y+v.z+v.w;
  float ss = v.x*v.x + v.y*v.y + v.z*v.z + v.w*v.w;
  #pragma unroll
  for (int off = 32; off; off >>= 1){ s += __shfl_xor(s, off); ss += __shfl_xor(ss, off); }
  float mu  = s * 0.00390625f;
  float var = ss * 0.00390625f - mu*mu;
  float rstd = 1.0f / sqrtf(var + 1e-6f);
  float4 g = *(const float4*)&ln_g[lane*4];
  float4 b = *(const float4*)&ln_b[lane*4];
  float4 o;
  o.x = (v.x-mu)*rstd*g.x + b.x;
  o.y = (v.y-mu)*rstd*g.y + b.y;
  o.z = (v.z-mu)*rstd*g.z + b.z;
  o.w = (v.w-mu)*rstd*g.w + b.w;
  *(float4*)&dco[(size_t)m*256 + lane*4] = o;
}

// ---------------- bn path: fused pw1->gelu->pw2 + residual (in place on bn_win) ----------
__global__ __launch_bounds__(256) void k_mlp(
  const float* __restrict__ normed, const float* __restrict__ W1T, const float* __restrict__ pw1_b,
  const float* __restrict__ W2T, const float* __restrict__ pw2_b, const float* __restrict__ lsg,
  float* __restrict__ io)
{
  __shared__ float xs[16*256];
  __shared__ float hb[16*256];
  int t = threadIdx.x;
  int tr = t >> 6, to = t & 63;
  size_t R0 = (size_t)blockIdx.x * 16;

  #pragma unroll
  for (int i = 0; i < 4; ++i){
    int e4 = t + 256*i;
    *(float4*)&xs[e4*4] = *(const float4*)&normed[R0*256 + (size_t)e4*4];
  }
  __syncthreads();

  float4 c0 = {0,0,0,0}, c1 = {0,0,0,0}, c2 = {0,0,0,0}, c3 = {0,0,0,0};

  for (int chunk = 0; chunk < 4; ++chunk){
    int cg = chunk*256 + to*4;
    float4 a0 = {0,0,0,0}, a1 = {0,0,0,0}, a2 = {0,0,0,0}, a3 = {0,0,0,0};
    for (int k = 0; k < 256; k += 4){
      float4 x0 = *(const float4*)&xs[(tr*4+0)*256 + k];
      float4 x1 = *(const float4*)&xs[(tr*4+1)*256 + k];
      float4 x2 = *(const float4*)&xs[(tr*4+2)*256 + k];
      float4 x3 = *(const float4*)&xs[(tr*4+3)*256 + k];
      { float4 wv = *(const float4*)&W1T[(size_t)(k+0)*1024 + cg];
        fma4s(a0, x0.x, wv); fma4s(a1, x1.x, wv); fma4s(a2, x2.x, wv); fma4s(a3, x3.x, wv); }
      { float4 wv = *(const float4*)&W1T[(size_t)(k+1)*1024 + cg];
        fma4s(a0, x0.y, wv); fma4s(a1, x1.y, wv); fma4s(a2, x2.y, wv); fma4s(a3, x3.y, wv); }
      { float4 wv = *(const float4*)&W1T[(size_t)(k+2)*1024 + cg];
        fma4s(a0, x0.z, wv); fma4s(a1, x1.z, wv); fma4s(a2, x2.z, wv); fma4s(a3, x3.z, wv); }
      { float4 wv = *(const float4*)&W1T[(size_t)(k+3)*1024 + cg];
        fma4s(a0, x0.w, wv); fma4s(a1, x1.w, wv); fma4s(a2, x2.w, wv); fma4s(a3, x3.w, wv); }
    }
    float4 b1 = *(const float4*)&pw1_b[cg];
    float4 h;
    h.x = gelu_f(a0.x + b1.x); h.y = gelu_f(a0.y + b1.y); h.z = gelu_f(a0.z + b1.z); h.w = gelu_f(a0.w + b1.w);
    *(float4*)&hb[(tr*4+0)*256 + to*4] = h;
    h.x = gelu_f(a1.x + b1.x); h.y = gelu_f(a1.y + b1.y); h.z = gelu_f(a1.z + b1.z); h.w = gelu_f(a1.w + b1.w);
    *(float4*)&hb[(tr*4+1)*256 + to*4] = h;
    h.x = gelu_f(a2.x + b1.x); h.y = gelu_f(a2.y + b1.y); h.z = gelu_f(a2.z + b1.z); h.w = gelu_f(a2.w + b1.w);
    *(float4*)&hb[(tr*4+2)*256 + to*4] = h;
    h.x = gelu_f(a3.x + b1.x); h.y = gelu_f(a3.y + b1.y); h.z = gelu_f(a3.z + b1.z); h.w = gelu_f(a3.w + b1.w);
    *(float4*)&hb[(tr*4+3)*256 + to*4] = h;
    __syncthreads();
    for (int hk = 0; hk < 256; hk += 4){
      float4 h0 = *(const float4*)&hb[(tr*4+0)*256 + hk];
      float4 h1v = *(const float4*)&hb[(tr*4+1)*256 + hk];
      float4 h2v = *(const float4*)&hb[(tr*4+2)*256 + hk];
      float4 h3v = *(const float4*)&hb[(tr*4+3)*256 + hk];
      { float4 wv = *(const float4*)&W2T[(size_t)(chunk*256 + hk + 0)*256 + to*4];
        fma4s(c0, h0.x, wv); fma4s(c1, h1v.x, wv); fma4s(c2, h2v.x, wv); fma4s(c3, h3v.x, wv); }
      { float4 wv = *(const float4*)&W2T[(size_t)(chunk*256 + hk + 1)*256 + to*4];
        fma4s(c0, h0.y, wv); fma4s(c1, h1v.y, wv); fma4s(c2, h2v.y, wv); fma4s(c3, h3v.y, wv); }
      { float4 wv = *(const float4*)&W2T[(size_t)(chunk*256 + hk + 2)*256 + to*4];
        fma4s(c0, h0.z, wv); fma4s(c1, h1v.z, wv); fma4s(c2, h2v.z, wv); fma4s(c3, h3v.z, wv); }
      { float4 wv = *(const float4*)&W2T[(size_t)(chunk*256 + hk + 3)*256 + to*4];
        fma4s(c0, h0.w, wv); fma4s(c1, h1v.w, wv); fma4s(c2, h2v.w, wv); fma4s(c3, h3v.w, wv); }
    }
    __syncthreads();
  }
  float4 b2 = *(const float4*)&pw2_b[to*4];
  float4 gm = *(const float4*)&lsg[to*4];
  #define EPI(RR, ACC) { size_t row = R0 + tr*4 + RR; \
    float4 res = *(const float4*)&io[row*256 + to*4]; \
    float4 o; \
    o.x = fmaf(ACC.x + b2.x, gm.x, res.x); \
    o.y = fmaf(ACC.y + b2.y, gm.y, res.y); \
    o.z = fmaf(ACC.z + b2.z, gm.z, res.z); \
    o.w = fmaf(ACC.w + b2.w, gm.w, res.w); \
    *(float4*)&io[row*256 + to*4] = o; }
  EPI(0, c0) EPI(1, c1) EPI(2, c2) EPI(3, c3)
  #undef EPI
}

// ---------------- bn path: 1x1 conv 256->128 + gelu + gaussian reduce ----------------
__global__ __launch_bounds__(256) void k_bnvec(
  const float* __restrict__ conv_out, const float* __restrict__ bnWT, const float* __restrict__ bn_b,
  const float* __restrict__ gbn, float* __restrict__ bn_vec)
{
  __shared__ float xrows[8*256];
  __shared__ float red[256];
  int n = blockIdx.x, t = threadIdx.x;
  int o = t & 127, rh = t >> 7;
  float vacc = 0.f;
  for (int pg = 0; pg < 16; ++pg){
    #pragma unroll
    for (int i = 0; i < 2; ++i){
      int e4 = t + 256*i;
      int pl = e4 >> 6;
      int cc = (e4 & 63)*4;
      int p = pg*8 + pl;
      float4 v = {0,0,0,0};
      if (p < 121) v = *(const float4*)&conv_out[((size_t)n*121 + p)*256 + cc];
      *(float4*)&xrows[pl*256 + cc] = v;
    }
    __syncthreads();
    float a0=0.f, a1=0.f, a2=0.f, a3=0.f;
    for (int c = 0; c < 256; c += 4){
      float w0 = bnWT[(c+0)*128 + o];
      float w1 = bnWT[(c+1)*128 + o];
      float w2 = bnWT[(c+2)*128 + o];
      float w3 = bnWT[(c+3)*128 + o];
      float4 x0 = *(const float4*)&xrows[(rh*4+0)*256 + c];
      float4 x1 = *(const float4*)&xrows[(rh*4+1)*256 + c];
      float4 x2 = *(const float4*)&xrows[(rh*4+2)*256 + c];
      float4 x3 = *(const float4*)&xrows[(rh*4+3)*256 + c];
      a0 = fmaf(x0.w,w3, fmaf(x0.z,w2, fmaf(x0.y,w1, fmaf(x0.x,w0, a0))));
      a1 = fmaf(x1.w,w3, fmaf(x1.z,w2, fmaf(x1.y,w1, fmaf(x1.x,w0, a1))));
      a2 = fmaf(x2.w,w3, fmaf(x2.z,w2, fmaf(x2.y,w1, fmaf(x2.x,w0, a2))));
      a3 = fmaf(x3.w,w3, fmaf(x3.z,w2, fmaf(x3.y,w1, fmaf(x3.x,w0, a3))));
    }
    float bb = bn_b[o];
    int pbase = pg*8 + rh*4;
    if (pbase+0 < 121) vacc += gbn[pbase+0] * gelu_f(a0 + bb);
    if (pbase+1 < 121) vacc += gbn[pbase+1] * gelu_f(a1 + bb);
    if (pbase+2 < 121) vacc += gbn[pbase+2] * gelu_f(a2 + bb);
    if (pbase+3 < 121) vacc += gbn[pbase+3] * gelu_f(a3 + bb);
    __syncthreads();
  }
  red[t] = vacc; __syncthreads();
  if (t < 128) bn_vec[n*128 + o] = red[t] + red[t+128];
}

// ---------------- head: feat -> MLP -> delta ; morphology ----------------
__global__ __launch_bounds__(256) void k_head(
  const float* __restrict__ bn_vec, const float* __restrict__ st_vec,
  const float* __restrict__ tr1_w, const float* __restrict__ tr1_b,
  const float* __restrict__ tr2_w, const float* __restrict__ tr2_b,
  const float* __restrict__ md_w, const float* __restrict__ md_b,
  const float* __restrict__ init_m,
  float* __restrict__ out)
{
  __shared__ float feat[192], h1s[256], h2s[256], dlt[961], yv[961];
  __shared__ float red[256];
  int n = blockIdx.x, t = threadIdx.x;
  float* morph_out = out;
  float* delta_out = out + 984064;      // 1024*961
  float* feat_out  = out + 1968128;     // 2*1024*961
  if (t < 128) feat[t] = bn_vec[n*128 + t];
  else if (t < 192) feat[t] = st_vec[n*64 + (t-128)];
  __syncthreads();
  if (t < 192) feat_out[(size_t)n*192 + t] = feat[t];
  {
    float a = tr1_b[t];
    const float* wr = &tr1_w[t*192];
    for (int k = 0; k < 192; ++k) a = fmaf(feat[k], wr[k], a);
    h1s[t] = gelu_f(a);
  }
  __syncthreads();
  {
    float a = tr2_b[t];
    const float* wr = &tr2_w[t*256];
    for (int k = 0; k < 256; ++k) a = fmaf(h1s[k], wr[k], a);
    h2s[t] = gelu_f(a);
  }
  __syncthreads();
  for (int j = t; j < 961; j += 256){
    float a = md_b[j];
    const float* wr = &md_w[(size_t)j*256];
    for (int k = 0; k < 256; ++k) a = fmaf(h2s[k], wr[k], a);
    float d = tanhf(a);
    dlt[j] = d;
    delta_out[(size_t)n*961 + j] = d;
  }
  // init morphology normalise sum
  float loc = 0.f;
  for (int j = t; j < 961; j += 256) loc += fmaxf(init_m[(size_t)n*961 + j], 0.f);
  red[t] = loc; __syncthreads();
  for (int s = 128; s > 0; s >>= 1){ if (t < s) red[t] += red[t+s]; __syncthreads(); }
  float s0 = red[0] + 1e-8f;
  __syncthreads();
  float loc2 = 0.f;
  for (int j = t; j < 961; j += 256){
    float imn = fmaxf(init_m[(size_t)n*961 + j], 0.f) / s0;
    float x = fmaxf(imn, 1e-8f);
    float base = x + logf(-expm1f(-x));
    float z = base + 1.5f * dlt[j];
    float y = fmaxf(z, 0.f) + log1pf(expf(-fabsf(z)));   // stable softplus
    yv[j] = y;
    loc2 += y;
  }
  red[t] = loc2; __syncthreads();
  for (int s = 128; s > 0; s >>= 1){ if (t < s) red[t] += red[t+s]; __syncthreads(); }
  float s1 = red[0] + 1e-8f;
  __syncthreads();
  for (int j = t; j < 961; j += 256) morph_out[(size_t)n*961 + j] = yv[j] / s1;
}

// ---------------- launch ----------------
extern "C" void kernel_launch(void* const* d_in, const int* in_sizes, int n_in,
                              void* d_out, int out_size, void* d_ws, size_t ws_size,
                              hipStream_t stream)
{
  const float* bott = (const float*)d_in[0];
  const float* vis  = (const float*)d_in[1];
  const float* pos  = (const float*)d_in[2];
  const float* initm= (const float*)d_in[3];
  const float* dw_w = (const float*)d_in[4];
  const float* dw_b = (const float*)d_in[5];
  const float* ln_g = (const float*)d_in[6];
  const float* ln_b = (const float*)d_in[7];
  const float* pw1_w= (const float*)d_in[8];
  const float* pw1_b= (const float*)d_in[9];
  const float* pw2_w= (const float*)d_in[10];
  const float* pw2_b= (const float*)d_in[11];
  const float* lsg  = (const float*)d_in[12];
  const float* bn_w = (const float*)d_in[13];
  const float* bn_b = (const float*)d_in[14];
  const float* st1_w= (const float*)d_in[15];
  const float* st1_b= (const float*)d_in[16];
  const float* st2_w= (const float*)d_in[17];
  const float* st2_b= (const float*)d_in[18];
  const float* tr1_w= (const float*)d_in[19];
  const float* tr1_b= (const float*)d_in[20];
  const float* tr2_w= (const float*)d_in[21];
  const float* tr2_b= (const float*)d_in[22];
  const float* md_w = (const float*)d_in[23];
  const float* md_b = (const float*)d_in[24];

  char* ws = (char*)d_ws;
  // big region (reused): st phase uses g1 (252 MB); then bn phase uses bn_win+dco (2x127 MB)
  float* g1     = (float*)(ws);
  float* bn_win = (float*)(ws);
  float* dco    = (float*)(ws + 126877696);          // 1024*121*256*4
  char*  S      = ws + 253755392;
  float* st_vec = (float*)(S);                        // 1024*64*4
  float* bn_vec = (float*)(S + 262144);               // 1024*128*4
  float* gbn    = (float*)(S + 786432);
  float* gst    = (float*)(S + 786944);
  float* W1T    = (float*)(S + 791040);               // 1 MB
  float* W2T    = (float*)(S + 1839616);              // 1 MB
  float* bnWT   = (float*)(S + 2888192);              // 128 KB
  float* Wt1    = (float*)(S + 3019264);              // 144 KB
  float* Wt2    = (float*)(S + 3166720);              // 144 KB

  hipMemsetAsync(st_vec, 0, 1024*64*sizeof(float), stream);
  k_gauss<<<1, 256, 0, stream>>>(gbn, gst);
  k_trans<<<256, 256, 0, stream>>>(pw1_w, pw2_w, bn_w, st1_w, st2_w, W1T, W2T, bnWT, Wt1, Wt2);

  // st path (uses big region as g1)
  k_st_conv1<<<dim3(1024, 8), 256, 0, stream>>>(vis, pos, Wt1, st1_b, g1);
  k_st_conv2<<<dim3(1024, 8), 256, 0, stream>>>(g1, gst, Wt2, st2_b, st_vec);

  // bn path (reuses big region)
  k_bn_gather<<<1024, 256, 0, stream>>>(bott, pos, bn_win);
  k_dwconv<<<dim3(1024, 4), 256, 0, stream>>>(bn_win, dw_w, dw_b, dco);
  k_ln<<<30976, 256, 0, stream>>>(dco, ln_g, ln_b);
  k_mlp<<<7744, 256, 0, stream>>>(dco, W1T, pw1_b, W2T, pw2_b, lsg, bn_win);
  k_bnvec<<<1024, 256, 0, stream>>>(bn_win, bnWT, bn_b, gbn, bn_vec);

  // head
  k_head<<<1024, 256, 0, stream>>>(bn_vec, st_vec, tr1_w, tr1_b, tr2_w, tr2_b,
                                   md_w, md_b, initm, (float*)d_out);
}

// Round 2
// 1844.733 us; speedup vs baseline: 3.5932x; 3.5932x over previous
//
#include <hip/hip_runtime.h>
#include <math.h>

// ---------------- constants ----------------
#define N_SRC 1024
#define VHW 1024
#define FHW 256

typedef __attribute__((ext_vector_type(8))) short short8;
typedef __attribute__((ext_vector_type(4))) float f32x4;

#define MFMA_B16(a,b,c) __builtin_amdgcn_mfma_f32_16x16x32_bf16((a),(b),(c),0,0,0)

__device__ __forceinline__ float gelu_f(float x){
  return 0.5f * x * (1.0f + erff(x * 0.70710678118654752440f));
}
__device__ __forceinline__ unsigned short f2bf(float f){
  union { float f; unsigned u; } x; x.f = f;
  unsigned r = x.u + 0x7fffu + ((x.u >> 16) & 1u);
  return (unsigned short)(r >> 16);
}
__device__ __forceinline__ float bf2f(unsigned short h){
  union { unsigned u; float f; } x; x.u = ((unsigned)h) << 16;
  return x.f;
}

// ---------------- gaussian tables (match numpy f64 then cast) ----------------
__global__ void k_gauss(float* __restrict__ gbn, float* __restrict__ gst){
  __shared__ double red[256];
  int t = threadIdx.x;
  {
    double v = 0.0;
    if (t < 121){
      int r = t / 11, c = t % 11;
      double y = -1.0 + 2.0 * (double)r / 10.0;
      double x = -1.0 + 2.0 * (double)c / 10.0;
      v = exp(-(x*x + y*y) / (2.0 * 0.4 * 0.4));
    }
    red[t] = v; __syncthreads();
    for (int s = 128; s > 0; s >>= 1){ if (t < s) red[t] += red[t+s]; __syncthreads(); }
    double sum = red[0];
    __syncthreads();
    if (t < 121) gbn[t] = (float)(v / sum);
    __syncthreads();
  }
  {
    double vals[4]; double loc = 0.0;
    #pragma unroll
    for (int i = 0; i < 4; ++i){
      int j = t + 256*i;
      double v = 0.0;
      if (j < 961){
        int r = j / 31, c = j % 31;
        double y = -1.0 + 2.0 * (double)r / 30.0;
        double x = -1.0 + 2.0 * (double)c / 30.0;
        v = exp(-(x*x + y*y) / (2.0 * 0.4 * 0.4));
      }
      vals[i] = v; loc += v;
    }
    red[t] = loc; __syncthreads();
    for (int s = 128; s > 0; s >>= 1){ if (t < s) red[t] += red[t+s]; __syncthreads(); }
    double sum = red[0];
    __syncthreads();
    #pragma unroll
    for (int i = 0; i < 4; ++i){
      int j = t + 256*i;
      if (j < 961) gst[j] = (float)(vals[i] / sum);
    }
  }
}

// ---------------- weight conversion / rearrangement ----------------
// W1b bf16 [1024][256] = pw1_w as-is; W2b bf16 [256][1024] = pw2_w as-is;
// Wc bf16 [64 co][9 tap][64 ci] from st_w [co][ci][3][3]; bnWT f32 [256][128].
__global__ void k_trans(const float* __restrict__ pw1_w, const float* __restrict__ pw2_w,
                        const float* __restrict__ bn_w,
                        const float* __restrict__ st1_w, const float* __restrict__ st2_w,
                        unsigned short* __restrict__ W1b, unsigned short* __restrict__ W2b,
                        float* __restrict__ bnWT,
                        unsigned short* __restrict__ Wc1, unsigned short* __restrict__ Wc2){
  int stride = gridDim.x * blockDim.x;
  int i0 = blockIdx.x * blockDim.x + threadIdx.x;
  for (int e = i0; e < 256*1024; e += stride) W1b[e] = f2bf(pw1_w[e]);
  for (int e = i0; e < 256*1024; e += stride) W2b[e] = f2bf(pw2_w[e]);
  for (int e = i0; e < 256*128; e += stride){ int c = e >> 7, o = e & 127; bnWT[e] = bn_w[o*256 + c]; }
  for (int e = i0; e < 64*576; e += stride){
    int co = e / 576, r = e % 576, d = r >> 6, ci = r & 63;
    Wc1[e] = f2bf(st1_w[(co*64 + ci)*9 + d]);
    Wc2[e] = f2bf(st2_w[(co*64 + ci)*9 + d]);
  }
}

// =======================================================================
// st path, MFMA im2col convs.
// Input tile LDS: 18 rows x 33 cols x 64 ch bf16, elem idx (p*64+ci)^((p&7)<<3).
// Wave w: co slice (w&1)*32 (2 co-tiles), m-tile half (w>>1).
// =======================================================================

__device__ __forceinline__ void conv_tiles_mfma(
    const unsigned short* __restrict__ in_t, const short8* B0, const short8* B1,
    int pb0, int pb1, int lk, f32x4& a00, f32x4& a01, f32x4& a10, f32x4& a11)
{
  #pragma unroll
  for (int ks = 0; ks < 18; ++ks){
    const int d = ks >> 1;
    const int dy = d / 3, dx = d - dy*3;
    const int cofs = (ks & 1)*32;
    int ci0 = cofs + lk*8;
    int p0 = pb0 + dy*33 + dx, p1 = pb1 + dy*33 + dx;
    short8 A0 = *(const short8*)&in_t[(p0*64 + ci0) ^ ((p0 & 7) << 3)];
    short8 A1 = *(const short8*)&in_t[(p1*64 + ci0) ^ ((p1 & 7) << 3)];
    a00 = MFMA_B16(A0, B0[ks], a00);
    a01 = MFMA_B16(A0, B1[ks], a01);
    a10 = MFMA_B16(A1, B0[ks], a10);
    a11 = MFMA_B16(A1, B1[ks], a11);
  }
}

// conv1: bilinear gather from vis -> LDS bf16; conv 64->64 + gelu -> g1 bf16 [n][31][31][64]
__global__ __launch_bounds__(256, 2) void k_stc1(
    const float* __restrict__ vis, const float* __restrict__ pos,
    const unsigned short* __restrict__ Wc1, const float* __restrict__ st1_b,
    unsigned short* __restrict__ g1)
{
  __shared__ unsigned short in_t[594*64];
  int n = blockIdx.x, band = blockIdx.y;
  int t = threadIdx.x;
  int w = t >> 6, l = t & 63, lr = l & 15, lk = l >> 4;
  int ybase = band*16 - 1;
  int rows_out = band ? 15 : 16;
  float px = pos[2*n], py = pos[2*n + 1];

  for (int e = t; e < 594*64; e += 256){
    int gc = e % 33;
    int rest = e / 33;
    int ci = rest & 63, gr = rest >> 6;
    int yy = ybase + gr, xx = gc - 1;
    float val = 0.0f;
    if (yy >= 0 && yy < 31 && xx >= 0 && xx < 31){
      float xsf = fminf(fmaxf(px + (float)(xx - 15), 0.0f), 1023.0f);
      float ysf = fminf(fmaxf(py + (float)(yy - 15), 0.0f), 1023.0f);
      int x0 = min((int)xsf, 1022);
      int y0 = min((int)ysf, 1022);
      float wx = xsf - (float)x0, wy = ysf - (float)y0;
      const float* b = vis + (size_t)ci * (VHW*VHW) + (size_t)y0 * VHW + x0;
      val = b[0]*(1.f-wy)*(1.f-wx) + b[1]*(1.f-wy)*wx + b[VHW]*wy*(1.f-wx) + b[VHW+1]*wy*wx;
    }
    int p = gr*33 + gc;
    in_t[(p*64 + ci) ^ ((p & 7) << 3)] = f2bf(val);
  }
  __syncthreads();

  int co0 = (w & 1) * 32;
  short8 B0[18], B1[18];
  #pragma unroll
  for (int ks = 0; ks < 18; ++ks){
    B0[ks] = *(const short8*)&Wc1[(co0 + lr)*576 + ks*32 + lk*8];
    B1[ks] = *(const short8*)&Wc1[(co0 + 16 + lr)*576 + ks*32 + lk*8];
  }
  int npos = rows_out * 31;
  int ntiles = (npos + 15) >> 4;
  int mstart = (w >> 1) * 16;
  int mend = min(mstart + 16, ntiles);
  float bc0 = st1_b[co0 + lr], bc1 = st1_b[co0 + 16 + lr];

  for (int mt = mstart; mt < mend; mt += 2){
    int s0 = min(mt*16 + lr, npos - 1);
    int s1 = min(mt*16 + 16 + lr, npos - 1);
    int ly0 = s0 / 31, x0p = s0 - ly0*31;
    int ly1 = s1 / 31, x1p = s1 - ly1*31;
    int pb0 = ly0*33 + x0p, pb1 = ly1*33 + x1p;
    f32x4 a00 = {0,0,0,0}, a01 = {0,0,0,0}, a10 = {0,0,0,0}, a11 = {0,0,0,0};
    conv_tiles_mfma(in_t, B0, B1, pb0, pb1, lk, a00, a01, a10, a11);
    #pragma unroll
    for (int i = 0; i < 4; ++i){
      int spo = mt*16 + lk*4 + i;
      if (spo < npos){
        int ly = spo / 31, xx = spo - ly*31;
        size_t o = ((size_t)(n*961 + (band*16 + ly)*31 + xx)) * 64;
        g1[o + co0 + lr]      = f2bf(gelu_f(a00[i] + bc0));
        g1[o + co0 + 16 + lr] = f2bf(gelu_f(a01[i] + bc1));
      }
      int sp1 = spo + 16;
      if (sp1 < npos && mt + 1 < ntiles){
        int ly = sp1 / 31, xx = sp1 - ly*31;
        size_t o = ((size_t)(n*961 + (band*16 + ly)*31 + xx)) * 64;
        g1[o + co0 + lr]      = f2bf(gelu_f(a10[i] + bc0));
        g1[o + co0 + 16 + lr] = f2bf(gelu_f(a11[i] + bc1));
      }
    }
  }
}

// conv2: copy g1 tile (zero-pad halo) -> LDS; conv + gelu + gaussian reduce -> st_vec
__global__ __launch_bounds__(256, 2) void k_stc2(
    const unsigned short* __restrict__ g1, const float* __restrict__ gst,
    const unsigned short* __restrict__ Wc2, const float* __restrict__ st2_b,
    float* __restrict__ st_vec)
{
  __shared__ unsigned short in_t[594*64];
  int n = blockIdx.x, band = blockIdx.y;
  int t = threadIdx.x;
  int w = t >> 6, l = t & 63, lr = l & 15, lk = l >> 4;
  int ybase = band*16 - 1;
  int rows_out = band ? 15 : 16;

  for (int c = t; c < 594*8; c += 256){
    int p = c >> 3, ci0 = (c & 7) * 8;
    int gr = p / 33, gc = p - gr*33;
    int yy = ybase + gr, xx = gc - 1;
    short8 v = {0,0,0,0,0,0,0,0};
    if (yy >= 0 && yy < 31 && xx >= 0 && xx < 31)
      v = *(const short8*)&g1[((size_t)(n*961 + yy*31 + xx))*64 + ci0];
    *(short8*)&in_t[(p*64 + ci0) ^ ((p & 7) << 3)] = v;
  }
  __syncthreads();

  int co0 = (w & 1) * 32;
  short8 B0[18], B1[18];
  #pragma unroll
  for (int ks = 0; ks < 18; ++ks){
    B0[ks] = *(const short8*)&Wc2[(co0 + lr)*576 + ks*32 + lk*8];
    B1[ks] = *(const short8*)&Wc2[(co0 + 16 + lr)*576 + ks*32 + lk*8];
  }
  int npos = rows_out * 31;
  int ntiles = (npos + 15) >> 4;
  int mstart = (w >> 1) * 16;
  int mend = min(mstart + 16, ntiles);
  float bc0 = st2_b[co0 + lr], bc1 = st2_b[co0 + 16 + lr];
  float vacc0 = 0.f, vacc1 = 0.f;

  for (int mt = mstart; mt < mend; mt += 2){
    int s0 = min(mt*16 + lr, npos - 1);
    int s1 = min(mt*16 + 16 + lr, npos - 1);
    int ly0 = s0 / 31, x0p = s0 - ly0*31;
    int ly1 = s1 / 31, x1p = s1 - ly1*31;
    int pb0 = ly0*33 + x0p, pb1 = ly1*33 + x1p;
    f32x4 a00 = {0,0,0,0}, a01 = {0,0,0,0}, a10 = {0,0,0,0}, a11 = {0,0,0,0};
    conv_tiles_mfma(in_t, B0, B1, pb0, pb1, lk, a00, a01, a10, a11);
    #pragma unroll
    for (int i = 0; i < 4; ++i){
      int spo = mt*16 + lk*4 + i;
      if (spo < npos){
        int ly = spo / 31, xx = spo - ly*31;
        float wt = gst[(band*16 + ly)*31 + xx];
        vacc0 += wt * gelu_f(a00[i] + bc0);
        vacc1 += wt * gelu_f(a01[i] + bc1);
      }
      int sp1 = spo + 16;
      if (sp1 < npos && mt + 1 < ntiles){
        int ly = sp1 / 31, xx = sp1 - ly*31;
        float wt = gst[(band*16 + ly)*31 + xx];
        vacc0 += wt * gelu_f(a10[i] + bc0);
        vacc1 += wt * gelu_f(a11[i] + bc1);
      }
    }
  }
  vacc0 += __shfl_xor(vacc0, 16); vacc0 += __shfl_xor(vacc0, 32);
  vacc1 += __shfl_xor(vacc1, 16); vacc1 += __shfl_xor(vacc1, 32);
  if (lk == 0){
    atomicAdd(&st_vec[n*64 + co0 + lr], vacc0);
    atomicAdd(&st_vec[n*64 + co0 + 16 + lr], vacc1);
  }
}

// ---------------- bn path: gather windows -> [n][121][256] f32 ----------------
__global__ __launch_bounds__(256) void k_bn_gather(
  const float* __restrict__ bott, const float* __restrict__ pos, float* __restrict__ bn_win)
{
  __shared__ float tile[121*65];
  int n = blockIdx.x, t = threadIdx.x;
  float pbx = (pos[2*n]   + 0.5f)*0.25f - 0.5f;
  float pby = (pos[2*n+1] + 0.5f)*0.25f - 0.5f;
  for (int c4 = 0; c4 < 4; ++c4){
    int ch0 = c4 * 64;
    for (int idx = t; idx < 121*64; idx += 256){
      int chl = idx / 121, p = idx % 121;
      int r = p / 11, c = p % 11;
      float xsf = fminf(fmaxf(pbx + (float)(c-5), 0.f), 255.f);
      float ysf = fminf(fmaxf(pby + (float)(r-5), 0.f), 255.f);
      int x0 = min(max((int)floorf(xsf),0), 254);
      int y0i = min(max((int)floorf(ysf),0), 254);
      float wx = xsf - (float)x0, wy = ysf - (float)y0i;
      const float* b = bott + (size_t)(ch0+chl)*(FHW*FHW) + y0i*FHW + x0;
      float val = b[0]*(1.f-wy)*(1.f-wx) + b[1]*(1.f-wy)*wx + b[FHW]*wy*(1.f-wx) + b[FHW+1]*wy*wx;
      tile[p*65 + chl] = val;
    }
    __syncthreads();
    for (int idx = t; idx < 121*64; idx += 256){
      int p = idx >> 6, j = idx & 63;
      bn_win[((size_t)n*121 + p)*256 + ch0 + j] = tile[p*65 + j];
    }
    __syncthreads();
  }
}

// ---------------- bn path: depthwise 7x7 + bias -> dco bf16 ----------------
__global__ __launch_bounds__(256) void k_dwconv(
  const float* __restrict__ bn_win, const float* __restrict__ dw_w, const float* __restrict__ dw_b,
  unsigned short* __restrict__ dcob)
{
  __shared__ float in_t[121*65];
  int n = blockIdx.x, c4 = blockIdx.y, t = threadIdx.x;
  int ch0 = c4*64;
  for (int idx = t; idx < 121*64; idx += 256){
    int p = idx >> 6, j = idx & 63;
    in_t[p*65 + j] = bn_win[((size_t)n*121 + p)*256 + ch0 + j];
  }
  int chl = t & 63;
  float w[49];
  #pragma unroll
  for (int k = 0; k < 49; ++k) w[k] = dw_w[(ch0 + chl)*49 + k];
  float bias = dw_b[ch0 + chl];
  __syncthreads();
  for (int sp = (t >> 6); sp < 121; sp += 4){
    int r = sp / 11, c = sp % 11;
    float a = bias;
    #pragma unroll
    for (int dy = 0; dy < 7; ++dy){
      int ry = r + dy - 3;
      if (ry < 0 || ry > 10) continue;
      #pragma unroll
      for (int dx = 0; dx < 7; ++dx){
        int cx = c + dx - 3;
        if (cx < 0 || cx > 10) continue;
        a = fmaf(in_t[(ry*11 + cx)*65 + chl], w[dy*7 + dx], a);
      }
    }
    dcob[((size_t)n*121 + sp)*256 + ch0 + chl] = f2bf(a);
  }
}

// ---------------- bn path: layernorm bf16 -> bf16, one wave per row ----------------
__global__ __launch_bounds__(256) void k_ln(
  const unsigned short* __restrict__ dcob, const float* __restrict__ ln_g, const float* __restrict__ ln_b,
  unsigned short* __restrict__ normb)
{
  int m = blockIdx.x*4 + (threadIdx.x >> 6);
  int lane = threadIdx.x & 63;
  ushort4 raw = *(const ushort4*)&dcob[(size_t)m*256 + lane*4];
  float4 v = { bf2f(raw.x), bf2f(raw.y), bf2f(raw.z), bf2f(raw.w) };
  float s  = v.x+v.y+v.z+v.w;
  float ss = v.x*v.x + v.y*v.y + v.z*v.z + v.w*v.w;
  #pragma unroll
  for (int off = 32; off; off >>= 1){ s += __shfl_xor(s, off); ss += __shfl_xor(ss, off); }
  float mu  = s * 0.00390625f;
  float var = ss * 0.00390625f - mu*mu;
  float rstd = 1.0f / sqrtf(var + 1e-6f);
  float4 g = *(const float4*)&ln_g[lane*4];
  float4 b = *(const float4*)&ln_b[lane*4];
  ushort4 o;
  o.x = f2bf((v.x-mu)*rstd*g.x + b.x);
  o.y = f2bf((v.y-mu)*rstd*g.y + b.y);
  o.z = f2bf((v.z-mu)*rstd*g.z + b.z);
  o.w = f2bf((v.w-mu)*rstd*g.w + b.w);
  *(ushort4*)&normb[(size_t)m*256 + lane*4] = o;
}

// ---------------- bn path: fused MFMA pw1->gelu->pw2 + residual ----------------
// 512 threads = 8 waves; block = 64 rows. Wave w: pw1 hidden cols [w*128,+128),
// pw2 out cols [w*32,+32). H staged in 128KB swizzled LDS.
__global__ __launch_bounds__(512, 2) void k_mlp(
  const unsigned short* __restrict__ Xb, const unsigned short* __restrict__ W1b,
  const float* __restrict__ pw1_b, const unsigned short* __restrict__ W2b,
  const float* __restrict__ pw2_b, const float* __restrict__ lsg,
  float* __restrict__ io)
{
  __shared__ unsigned short Hs[64*1024];
  int t = threadIdx.x;
  int w = t >> 6, l = t & 63, lr = l & 15, lk = l >> 4;
  size_t m0 = (size_t)blockIdx.x * 64;

  f32x4 acc[4][8];
  #pragma unroll
  for (int mt = 0; mt < 4; ++mt)
    #pragma unroll
    for (int nt = 0; nt < 8; ++nt) acc[mt][nt] = (f32x4){0,0,0,0};

  #pragma unroll
  for (int ks = 0; ks < 8; ++ks){
    short8 a[4];
    #pragma unroll
    for (int mt = 0; mt < 4; ++mt)
      a[mt] = *(const short8*)&Xb[(m0 + mt*16 + lr)*256 + ks*32 + lk*8];
    #pragma unroll
    for (int nt = 0; nt < 8; ++nt){
      short8 b = *(const short8*)&W1b[(size_t)(w*128 + nt*16 + lr)*256 + ks*32 + lk*8];
      #pragma unroll
      for (int mt = 0; mt < 4; ++mt)
        acc[mt][nt] = MFMA_B16(a[mt], b, acc[mt][nt]);
    }
  }

  #pragma unroll
  for (int nt = 0; nt < 8; ++nt){
    int hk = w*128 + nt*16 + lr;
    float b1 = pw1_b[hk];
    #pragma unroll
    for (int mt = 0; mt < 4; ++mt)
      #pragma unroll
      for (int i = 0; i < 4; ++i){
        int row = mt*16 + lk*4 + i;
        Hs[(row*1024 + hk) ^ ((row & 7) << 3)] = f2bf(gelu_f(acc[mt][nt][i] + b1));
      }
  }
  __syncthreads();

  f32x4 c[4][2];
  #pragma unroll
  for (int mt = 0; mt < 4; ++mt){ c[mt][0] = (f32x4){0,0,0,0}; c[mt][1] = (f32x4){0,0,0,0}; }

  #pragma unroll
  for (int ks = 0; ks < 32; ++ks){
    short8 a[4];
    #pragma unroll
    for (int mt = 0; mt < 4; ++mt){
      int row = mt*16 + lr;
      a[mt] = *(const short8*)&Hs[(row*1024 + ks*32 + lk*8) ^ ((row & 7) << 3)];
    }
    #pragma unroll
    for (int ot = 0; ot < 2; ++ot){
      short8 b = *(const short8*)&W2b[(size_t)(w*32 + ot*16 + lr)*1024 + ks*32 + lk*8];
      #pragma unroll
      for (int mt = 0; mt < 4; ++mt)
        c[mt][ot] = MFMA_B16(a[mt], b, c[mt][ot]);
    }
  }

  #pragma unroll
  for (int ot = 0; ot < 2; ++ot){
    int col = w*32 + ot*16 + lr;
    float b2 = pw2_b[col], gm = lsg[col];
    #pragma unroll
    for (int mt = 0; mt < 4; ++mt)
      #pragma unroll
      for (int i = 0; i < 4; ++i){
        size_t row = m0 + mt*16 + lk*4 + i;
        float* p = &io[row*256 + col];
        *p = fmaf(c[mt][ot][i] + b2, gm, *p);
      }
  }
}

// ---------------- bn path: 1x1 conv 256->128 + gelu + gaussian reduce ----------------
__global__ __launch_bounds__(256) void k_bnvec(
  const float* __restrict__ conv_out, const float* __restrict__ bnWT, const float* __restrict__ bn_b,
  const float* __restrict__ gbn, float* __restrict__ bn_vec)
{
  __shared__ float xrows[8*256];
  __shared__ float red[256];
  int n = blockIdx.x, t = threadIdx.x;
  int o = t & 127, rh = t >> 7;
  float vacc = 0.f;
  for (int pg = 0; pg < 16; ++pg){
    #pragma unroll
    for (int i = 0; i < 2; ++i){
      int e4 = t + 256*i;
      int pl = e4 >> 6;
      int cc = (e4 & 63)*4;
      int p = pg*8 + pl;
      float4 v = {0,0,0,0};
      if (p < 121) v = *(const float4*)&conv_out[((size_t)n*121 + p)*256 + cc];
      *(float4*)&xrows[pl*256 + cc] = v;
    }
    __syncthreads();
    float a0=0.f, a1=0.f, a2=0.f, a3=0.f;
    for (int cidx = 0; cidx < 256; cidx += 4){
      float w0 = bnWT[(cidx+0)*128 + o];
      float w1 = bnWT[(cidx+1)*128 + o];
      float w2 = bnWT[(cidx+2)*128 + o];
      float w3 = bnWT[(cidx+3)*128 + o];
      float4 x0 = *(const float4*)&xrows[(rh*4+0)*256 + cidx];
      float4 x1 = *(const float4*)&xrows[(rh*4+1)*256 + cidx];
      float4 x2 = *(const float4*)&xrows[(rh*4+2)*256 + cidx];
      float4 x3 = *(const float4*)&xrows[(rh*4+3)*256 + cidx];
      a0 = fmaf(x0.w,w3, fmaf(x0.z,w2, fmaf(x0.y,w1, fmaf(x0.x,w0, a0))));
      a1 = fmaf(x1.w,w3, fmaf(x1.z,w2, fmaf(x1.y,w1, fmaf(x1.x,w0, a1))));
      a2 = fmaf(x2.w,w3, fmaf(x2.z,w2, fmaf(x2.y,w1, fmaf(x2.x,w0, a2))));
      a3 = fmaf(x3.w,w3, fmaf(x3.z,w2, fmaf(x3.y,w1, fmaf(x3.x,w0, a3))));
    }
    float bb = bn_b[o];
    int pbase = pg*8 + rh*4;
    if (pbase+0 < 121) vacc += gbn[pbase+0] * gelu_f(a0 + bb);
    if (pbase+1 < 121) vacc += gbn[pbase+1] * gelu_f(a1 + bb);
    if (pbase+2 < 121) vacc += gbn[pbase+2] * gelu_f(a2 + bb);
    if (pbase+3 < 121) vacc += gbn[pbase+3] * gelu_f(a3 + bb);
    __syncthreads();
  }
  red[t] = vacc; __syncthreads();
  if (t < 128) bn_vec[n*128 + o] = red[t] + red[t+128];
}

// ---------------- head: feat -> MLP -> delta ; morphology ----------------
__global__ __launch_bounds__(256) void k_head(
  const float* __restrict__ bn_vec, const float* __restrict__ st_vec,
  const float* __restrict__ tr1_w, const float* __restrict__ tr1_b,
  const float* __restrict__ tr2_w, const float* __restrict__ tr2_b,
  const float* __restrict__ md_w, const float* __restrict__ md_b,
  const float* __restrict__ init_m,
  float* __restrict__ out)
{
  __shared__ float feat[192], h1s[256], h2s[256], dlt[961], yv[961];
  __shared__ float red[256];
  int n = blockIdx.x, t = threadIdx.x;
  float* morph_out = out;
  float* delta_out = out + 984064;
  float* feat_out  = out + 1968128;
  if (t < 128) feat[t] = bn_vec[n*128 + t];
  else if (t < 192) feat[t] = st_vec[n*64 + (t-128)];
  __syncthreads();
  if (t < 192) feat_out[(size_t)n*192 + t] = feat[t];
  {
    float a = tr1_b[t];
    const float* wr = &tr1_w[t*192];
    for (int k = 0; k < 192; ++k) a = fmaf(feat[k], wr[k], a);
    h1s[t] = gelu_f(a);
  }
  __syncthreads();
  {
    float a = tr2_b[t];
    const float* wr = &tr2_w[t*256];
    for (int k = 0; k < 256; ++k) a = fmaf(h1s[k], wr[k], a);
    h2s[t] = gelu_f(a);
  }
  __syncthreads();
  for (int j = t; j < 961; j += 256){
    float a = md_b[j];
    const float* wr = &md_w[(size_t)j*256];
    for (int k = 0; k < 256; ++k) a = fmaf(h2s[k], wr[k], a);
    float d = tanhf(a);
    dlt[j] = d;
    delta_out[(size_t)n*961 + j] = d;
  }
  float loc = 0.f;
  for (int j = t; j < 961; j += 256) loc += fmaxf(init_m[(size_t)n*961 + j], 0.f);
  red[t] = loc; __syncthreads();
  for (int s = 128; s > 0; s >>= 1){ if (t < s) red[t] += red[t+s]; __syncthreads(); }
  float s0 = red[0] + 1e-8f;
  __syncthreads();
  float loc2 = 0.f;
  for (int j = t; j < 961; j += 256){
    float imn = fmaxf(init_m[(size_t)n*961 + j], 0.f) / s0;
    float x = fmaxf(imn, 1e-8f);
    float base = x + logf(-expm1f(-x));
    float z = base + 1.5f * dlt[j];
    float y = fmaxf(z, 0.f) + log1pf(expf(-fabsf(z)));
    yv[j] = y;
    loc2 += y;
  }
  red[t] = loc2; __syncthreads();
  for (int s = 128; s > 0; s >>= 1){ if (t < s) red[t] += red[t+s]; __syncthreads(); }
  float s1 = red[0] + 1e-8f;
  __syncthreads();
  for (int j = t; j < 961; j += 256) morph_out[(size_t)n*961 + j] = yv[j] / s1;
}

// ---------------- launch ----------------
extern "C" void kernel_launch(void* const* d_in, const int* in_sizes, int n_in,
                              void* d_out, int out_size, void* d_ws, size_t ws_size,
                              hipStream_t stream)
{
  const float* bott = (const float*)d_in[0];
  const float* vis  = (const float*)d_in[1];
  const float* pos  = (const float*)d_in[2];
  const float* initm= (const float*)d_in[3];
  const float* dw_w = (const float*)d_in[4];
  const float* dw_b = (const float*)d_in[5];
  const float* ln_g = (const float*)d_in[6];
  const float* ln_b = (const float*)d_in[7];
  const float* pw1_w= (const float*)d_in[8];
  const float* pw1_b= (const float*)d_in[9];
  const float* pw2_w= (const float*)d_in[10];
  const float* pw2_b= (const float*)d_in[11];
  const float* lsg  = (const float*)d_in[12];
  const float* bn_w = (const float*)d_in[13];
  const float* bn_b = (const float*)d_in[14];
  const float* st1_w= (const float*)d_in[15];
  const float* st1_b= (const float*)d_in[16];
  const float* st2_w= (const float*)d_in[17];
  const float* st2_b= (const float*)d_in[18];
  const float* tr1_w= (const float*)d_in[19];
  const float* tr1_b= (const float*)d_in[20];
  const float* tr2_w= (const float*)d_in[21];
  const float* tr2_b= (const float*)d_in[22];
  const float* md_w = (const float*)d_in[23];
  const float* md_b = (const float*)d_in[24];

  char* ws = (char*)d_ws;
  // Region A (127MB): g1 bf16 (st phase) then bn_win f32 (bn phase, also MLP residual io)
  unsigned short* g1     = (unsigned short*)(ws);
  float*          bn_win = (float*)(ws);
  // Region B (63.5MB): dco bf16
  unsigned short* dcob   = (unsigned short*)(ws + 126877696);
  // Region C (63.5MB): normed bf16
  unsigned short* normb  = (unsigned short*)(ws + 190316544);
  char* S = ws + 253755392;
  float* st_vec = (float*)(S);                        // 256KB
  float* bn_vec = (float*)(S + 262144);               // 512KB
  float* gbn    = (float*)(S + 786432);
  float* gst    = (float*)(S + 786944);
  unsigned short* W1b = (unsigned short*)(S + 791040);   // 512KB
  unsigned short* W2b = (unsigned short*)(S + 1315328);  // 512KB
  unsigned short* Wc1 = (unsigned short*)(S + 1839616);  // 72KB
  unsigned short* Wc2 = (unsigned short*)(S + 1913344);  // 72KB
  float* bnWT = (float*)(S + 1987072);                   // 128KB

  hipMemsetAsync(st_vec, 0, 1024*64*sizeof(float), stream);
  k_gauss<<<1, 256, 0, stream>>>(gbn, gst);
  k_trans<<<256, 256, 0, stream>>>(pw1_w, pw2_w, bn_w, st1_w, st2_w, W1b, W2b, bnWT, Wc1, Wc2);

  // st path (region A = g1)
  k_stc1<<<dim3(1024, 2), 256, 0, stream>>>(vis, pos, Wc1, st1_b, g1);
  k_stc2<<<dim3(1024, 2), 256, 0, stream>>>(g1, gst, Wc2, st2_b, st_vec);

  // bn path (region A -> bn_win)
  k_bn_gather<<<1024, 256, 0, stream>>>(bott, pos, bn_win);
  k_dwconv<<<dim3(1024, 4), 256, 0, stream>>>(bn_win, dw_w, dw_b, dcob);
  k_ln<<<30976, 256, 0, stream>>>(dcob, ln_g, ln_b, normb);
  k_mlp<<<1936, 512, 0, stream>>>(normb, W1b, pw1_b, W2b, pw2_b, lsg, bn_win);
  k_bnvec<<<1024, 256, 0, stream>>>(bn_win, bnWT, bn_b, gbn, bn_vec);

  // head
  k_head<<<1024, 256, 0, stream>>>(bn_vec, st_vec, tr1_w, tr1_b, tr2_w, tr2_b,
                                   md_w, md_b, initm, (float*)d_out);
}